// Round 11
// baseline (59.314 us; speedup 1.0000x reference)
//
#include <hip/hip_runtime.h>
#include <hip/hip_bf16.h>
#include <float.h>

#define N 8192
#define D 128
#define BM 256                       // rows per block: 4 waves x 64
#define BN 64                        // cols per LDS tile
#define GY 16                        // col-chunks (grid.y)
#define GZ 2                         // DIAGNOSTIC: work duplication factor
#define COLS_PER_BLOCK (N / GY)      // 512
#define TILES (COLS_PER_BLOCK / BN)  // 8
#define NPART (GY * GZ)              // 32 partial slots per row
#define LOSS_BLOCKS (N / 256)        // 32

typedef unsigned short u16;
typedef unsigned int u32;
typedef __attribute__((ext_vector_type(8))) short bf16x8;
typedef __attribute__((ext_vector_type(4))) float f32x4;

typedef const __attribute__((address_space(1))) u32 glb_u32;
typedef __attribute__((address_space(3))) u32 lds_u32;

__device__ inline u16 f32_to_bf16_rtne(float f) {
  union { float f; unsigned int u; } c; c.f = f;
  unsigned int u = c.u;
  u += 0x7FFFu + ((u >> 16) & 1u);
  return (u16)(u >> 16);
}

// ---------------- kernel 1: f32 -> bf16 convert (+ counter zero) -------------
__global__ __launch_bounds__(256) void convert_kernel(const float* __restrict__ P,
                                                      u16* __restrict__ Pb,
                                                      int* __restrict__ counter) {
  int i = blockIdx.x * 256 + threadIdx.x;
  if (i == 0) counter[0] = 0;                  // re-armed every launch (replay-safe)
  float4 v = reinterpret_cast<const float4*>(P)[i];
  uint2 o;
  o.x = (unsigned)f32_to_bf16_rtne(v.x) | ((unsigned)f32_to_bf16_rtne(v.y) << 16);
  o.y = (unsigned)f32_to_bf16_rtne(v.z) | ((unsigned)f32_to_bf16_rtne(v.w) << 16);
  reinterpret_cast<uint2*>(Pb)[i] = o;
}

// ---------------- kernel 2 body: EXACT r3/r10 margin (best measured) ---------
// 3-deep pipelined fused sim + min/max. 4 waves x 64 rows (reuse-4), counted
// vmcnt, one barrier per tile. Swizzle (validated r2-r10):
// LDS_off(c,o) = c*256 + (o ^ ((c&15)<<4)), inverse applied on the global
// source at stage time, same XOR on the ds_read address (rule 21).
template <bool DIAG>
__device__ __forceinline__ void pipeline(const char* __restrict__ pbb,
                                         const int* __restrict__ y,
                                         float* __restrict__ pmin,
                                         float* __restrict__ pmax,
                                         char* ldsB, int* ldsY,
                                         int R0, int C0, int slot) {
  const int tid  = threadIdx.x;
  const int w    = tid >> 6;
  const int lane = tid & 63;
  const int c15  = lane & 15;
  const int g    = lane >> 4;

  // y for the block's 512 cols (wave w: ints [w*128, +128), 2 glds)
  {
    const int* gy = y + C0 + w * 128 + lane;
    lds_u32* dst = (lds_u32*)(ldsY + w * 128);
    __builtin_amdgcn_global_load_lds((glb_u32*)gy,        dst,      4, 0, 0);
    __builtin_amdgcn_global_load_lds((glb_u32*)(gy + 64), dst + 64, 4, 0, 0);
  }

  // stage tile t into buffer buf: 16KB B, 4 glds x 1KB per wave, uniform count
  auto STAGE = [&](int buf, int t) {
    const char* gb = pbb + (size_t)(C0 + t * BN) * 256;
    char* base = ldsB + buf * (BN * 256);
#pragma unroll
    for (int j = 0; j < 4; ++j) {
      const int L = ((w * 4 + j) * 64 + lane) * 16;    // linear LDS byte
      const int c = L >> 8;
      const int o = L & 255;
      const int src = c * 256 + (o ^ ((c & 15) << 4)); // inverse-swizzled source
      __builtin_amdgcn_global_load_lds((glb_u32*)(gb + src),
                                       (lds_u32*)(base + (w * 4 + j) * 1024), 16, 0, 0);
    }
  };

  STAGE(0, 0);
  STAGE(1, 1);

  // A fragments: 4 rowgroups x 16 rows, K=128 (64 VGPRs, resident)
  bf16x8 afrag[4][4];
#pragma unroll
  for (int rg = 0; rg < 4; ++rg) {
    const char* ap = pbb + (size_t)(R0 + w * 64 + rg * 16 + c15) * 256 + g * 16;
#pragma unroll
    for (int kk = 0; kk < 4; ++kk)
      afrag[rg][kk] = *reinterpret_cast<const bf16x8*>(ap + kk * 64);
  }

  int rowI[4][4], yrow[4][4];
#pragma unroll
  for (int rg = 0; rg < 4; ++rg)
#pragma unroll
    for (int r = 0; r < 4; ++r) {
      rowI[rg][r] = R0 + w * 64 + rg * 16 + g * 4 + r;
      yrow[rg][r] = y[rowI[rg][r]];
    }

  float mins[4][4], maxd[4][4];
#pragma unroll
  for (int rg = 0; rg < 4; ++rg)
#pragma unroll
    for (int r = 0; r < 4; ++r) { mins[rg][r] = FLT_MAX; maxd[rg][r] = -FLT_MAX; }

#pragma unroll 1
  for (int t = 0; t < TILES; ++t) {
    // counted vmcnt: stage(t) drained (FIFO), stage(t+1)'s 4 loads in flight
    if (t + 1 < TILES) asm volatile("s_waitcnt vmcnt(4)" ::: "memory");
    else               asm volatile("s_waitcnt vmcnt(0)" ::: "memory");
    __builtin_amdgcn_s_barrier();          // all waves' stage(t) landed;
                                           // buf[(t+2)%3] free (was read in t-1)
    if (t + 2 < TILES) STAGE((t + 2) % 3, t + 2);

    const char* Bb = ldsB + (t % 3) * (BN * 256);
    const int ct0 = t * BN;                // col offset within block
#pragma unroll
    for (int s = 0; s < 4; ++s) {
      const int c = s * 16 + c15;
      bf16x8 bf[4];
#pragma unroll
      for (int kk = 0; kk < 4; ++kk) {
        const int off = c * 256 + (((g * 16) | (kk * 64)) ^ (c15 << 4));
        bf[kk] = *reinterpret_cast<const bf16x8*>(Bb + off);
      }
      f32x4 acc[4];
#pragma unroll
      for (int rg = 0; rg < 4; ++rg) acc[rg] = (f32x4){0.f, 0.f, 0.f, 0.f};
#pragma unroll
      for (int kk = 0; kk < 4; ++kk)
#pragma unroll
        for (int rg = 0; rg < 4; ++rg)
          acc[rg] = __builtin_amdgcn_mfma_f32_16x16x32_bf16(afrag[rg][kk], bf[kk],
                                                            acc[rg], 0, 0, 0);
      const int colB = ct0 + c;
      const int col  = C0 + colB;
      const int ycol = ldsY[colB];
#pragma unroll
      for (int rg = 0; rg < 4; ++rg)
#pragma unroll
        for (int r = 0; r < 4; ++r) {
          const float v = acc[rg][r];
          const bool same = (ycol == yrow[rg][r]);
          bool okmin = same;
          if (DIAG) okmin = same && (col != rowI[rg][r]);
          const float cmin = okmin ? v : FLT_MAX;
          const float cmax = same ? -FLT_MAX : v;
          mins[rg][r] = fminf(mins[rg][r], cmin);
          maxd[rg][r] = fmaxf(maxd[rg][r], cmax);
        }
    }
  }

  // butterfly over the 16 col-lanes (bits 0-3)
#pragma unroll
  for (int off = 1; off < 16; off <<= 1)
#pragma unroll
    for (int rg = 0; rg < 4; ++rg)
#pragma unroll
      for (int r = 0; r < 4; ++r) {
        mins[rg][r] = fminf(mins[rg][r], __shfl_xor(mins[rg][r], off, 64));
        maxd[rg][r] = fmaxf(maxd[rg][r], __shfl_xor(maxd[rg][r], off, 64));
      }

  if (c15 == 0) {
#pragma unroll
    for (int rg = 0; rg < 4; ++rg)
#pragma unroll
      for (int r = 0; r < 4; ++r) {
        pmin[(size_t)slot * N + rowI[rg][r]] = mins[rg][r];
        pmax[(size_t)slot * N + rowI[rg][r]] = maxd[rg][r];
      }
  }
}

// DIAGNOSTIC (this round only): gridDim.z = 2 duplicates the full workload
// inside ONE dispatch (disjoint slot sets; min/max idempotent; deterministic)
// so margin_main outranks the ~40us harness fills in rocprof and we finally
// read its counters. dur_us - 39.3 = margin's exact marginal cost.
__global__ __launch_bounds__(256, 2) void margin_main(const u16* __restrict__ Pb,
                                                      const int* __restrict__ y,
                                                      float* __restrict__ pmin,
                                                      float* __restrict__ pmax) {
  __shared__ __align__(16) char ldsB[3][BN * 256];   // 48 KB, 3-deep
  __shared__ int ldsY[COLS_PER_BLOCK];               // 2 KB
  const int R0 = blockIdx.x * BM;
  const int C0 = blockIdx.y * COLS_PER_BLOCK;
  const int slot = blockIdx.z * GY + blockIdx.y;
  if ((unsigned)(R0 - C0) < (unsigned)COLS_PER_BLOCK)
    pipeline<true>((const char*)Pb, y, pmin, pmax, &ldsB[0][0], ldsY, R0, C0, slot);
  else
    pipeline<false>((const char*)Pb, y, pmin, pmax, &ldsB[0][0], ldsY, R0, C0, slot);
}

// ------- kernel 3: combine partials + hinge + deterministic final mean -------
__global__ __launch_bounds__(256) void loss_final(const float* __restrict__ pmin,
                                                  const float* __restrict__ pmax,
                                                  float* __restrict__ partial,
                                                  int* __restrict__ counter,
                                                  float* __restrict__ out) {
  const int row = blockIdx.x * 256 + threadIdx.x;
  float mn = FLT_MAX, mx = -FLT_MAX;
#pragma unroll
  for (int s = 0; s < NPART; ++s) {            // slot-major: coalesced
    mn = fminf(mn, pmin[(size_t)s * N + row]);
    mx = fmaxf(mx, pmax[(size_t)s * N + row]);
  }
  if (mn == FLT_MAX)  mn = 0.f;                // row has no same-class partner
  if (mx == -FLT_MAX) mx = 0.f;                // row has no diff-class partner
  float loss = fmaxf(0.f, mn + mx + 1.0f);     // TAU = 1.0

#pragma unroll
  for (int off = 32; off >= 1; off >>= 1)
    loss += __shfl_down(loss, off, 64);
  __shared__ float wsum[4];
  if ((threadIdx.x & 63) == 0) wsum[threadIdx.x >> 6] = loss;
  __syncthreads();
  if (threadIdx.x == 0) {
    partial[blockIdx.x] = wsum[0] + wsum[1] + wsum[2] + wsum[3];
    __threadfence();                           // partial visible device-wide
    if (atomicAdd(counter, 1) == LOSS_BLOCKS - 1) {
      __threadfence();                         // acquire all partials
      float tot = 0.f;
#pragma unroll
      for (int b = 0; b < LOSS_BLOCKS; ++b) tot += partial[b];
      out[0] = tot / (float)N;
    }
  }
}

extern "C" void kernel_launch(void* const* d_in, const int* in_sizes, int n_in,
                              void* d_out, int out_size, void* d_ws, size_t ws_size,
                              hipStream_t stream) {
  const float* P = (const float*)d_in[0];
  const int*   y = (const int*)d_in[1];
  float* out = (float*)d_out;

  // ws: Pb (2MB) | pmin (1MB) | pmax (1MB) | partial (128B) | counter
  u16*   Pb      = (u16*)d_ws;
  float* pmin    = (float*)((char*)d_ws + (size_t)N * D * sizeof(u16));
  float* pmax    = pmin + (size_t)N * NPART;
  float* partial = pmax + (size_t)N * NPART;
  int*   counter = (int*)(partial + LOSS_BLOCKS);

  convert_kernel<<<dim3(N * D / 4 / 256), 256, 0, stream>>>(P, Pb, counter);
  margin_main<<<dim3(N / BM, GY, GZ), 256, 0, stream>>>(Pb, y, pmin, pmax);
  loss_final<<<dim3(LOSS_BLOCKS), 256, 0, stream>>>(pmin, pmax, partial, counter, out);
}